// Round 10
// baseline (263.197 us; speedup 1.0000x reference)
//
#include <hip/hip_runtime.h>
#include <math.h>

#define NF 512         // feature count
#define NP 118         // raw params per feature
#define NPPAD 126      // padded: L0 at 0 (+1 pad), middle li at 10+16*(li-1), final at 122
#define FT 32          // features per block tile (16 feature-pairs -> full 128B lines)
#define NPF 16         // feature-pairs per tile
#define ROWS 4         // rows per thread
#define BLOCK_ROWS 64  // (256/NPF) rowgroups * ROWS
#define TBL_N 2048     // tanh secant bins over ~[-8,8] (h=1/128, accuracy-proven)
#define WS_NEED ((size_t)(NPPAD * NF + 2 * TBL_N) * sizeof(float))

typedef float v2f __attribute__((ext_vector_type(2)));

// plain packed fp32 FMA (feature-pair packing: every operand is a true pair)
__device__ __forceinline__ v2f f_PP(v2f a, v2f b, v2f c) {
    v2f d; asm("v_pk_fma_f32 %0, %1, %2, %3" : "=v"(d) : "v"(a), "v"(b), "v"(c)); return d;
}

__device__ __forceinline__ float fast_rcp(float x) { return __builtin_amdgcn_rcpf(x); }
__device__ __forceinline__ float exp2_fast(float x) {
#if __has_builtin(__builtin_amdgcn_exp2f)
    return __builtin_amdgcn_exp2f(x);
#else
    return __expf(x * 0.6931471805599453f);
#endif
}

// exp-path tanh (trans pipe): 3 VALU + 2 trans per scalar
__device__ __forceinline__ float tanh_exp1(float x) {
    float e = exp2_fast(x * 2.8853900817779268f);
    return fmaf(-2.0f, fast_rcp(e + 1.0f), 1.0f);
}
__device__ __forceinline__ v2f tanh_exp_pair(v2f a) {
    v2f t; t.x = tanh_exp1(a.x); t.y = tanh_exp1(a.y); return t;
}
__device__ __forceinline__ float sigmoid1(float x) {
    return fast_rcp(1.0f + exp2_fast(x * -1.4426950408889634f));
}

// LUT-path tanh: secant table gather from GLOBAL (L1-resident 16KB table, VMEM pipe)
__device__ __forceinline__ v2f tanh_lut_pair(v2f a, const v2f* __restrict__ tbl,
                                             v2f K128, v2f KIdx) {
    v2f xi = f_PP(a, K128, KIdx);
    unsigned i0 = (unsigned)__builtin_amdgcn_fmed3f(xi.x, 0.0f, (float)(TBL_N - 1));
    unsigned i1 = (unsigned)__builtin_amdgcn_fmed3f(xi.y, 0.0f, (float)(TBL_N - 1));
    v2f g0 = tbl[i0];
    v2f g1 = tbl[i1];
    v2f t;
    t.x = fmaf(a.x, g0.x, g0.y);
    t.y = fmaf(a.y, g1.x, g1.y);
    return t;
}

// ---- parameter transform ----
__device__ __forceinline__ float transform_one(float v, int j) {
    int cls;
    if (j < 3) cls = 0;
    else if (j < 6) cls = 1;
    else if (j < 9) cls = 2;
    else if (j < 114) { int k = (j - 9) % 15; cls = (k < 9) ? 0 : ((k < 12) ? 1 : 2); }
    else if (j < 117) cls = 0;
    else cls = 1;
    if (cls == 0) return fmaxf(v, 0.0f) + log1pf(expf(-fabsf(v)));  // stable softplus
    if (cls == 2) return tanhf(v);
    return v;
}

__device__ __forceinline__ bool map_padded(int jp, int* j) {
    if (jp < 9) { *j = jp; return true; }
    if (jp == 9) return false;
    if (jp < 122) {
        int k = (jp - 10) & 15, li = (jp - 10) >> 4;
        if (k == 15) return false;
        *j = 9 + 15 * li + k;
        return true;
    }
    *j = 114 + (jp - 122);
    return true;
}

__device__ __forceinline__ float transform_padded(const float* __restrict__ prow, int jp) {
    int j;
    if (!map_padded(jp, &j)) return 0.0f;
    return transform_one(prow[j], j);
}

// secant over centered bin b: x in [(b-1024.5)/128, (b-1023.5)/128)
__device__ __forceinline__ void tbl_entry(int b, float* s, float* c) {
    float xl = (float)b * (1.0f / 128.0f) - (1024.5f / 128.0f);
    float xr = xl + (1.0f / 128.0f);
    float t0 = tanhf(xl), t1 = tanhf(xr);
    float sl = (t1 - t0) * 128.0f;
    *s = sl;
    *c = fmaf(-sl, xl, t0);
}

// Kernel 1: padded+transformed params transposed t[jp*NF+f], then (s,c) table.
__global__ void xform_kernel(const float* __restrict__ p, float* __restrict__ t) {
    int idx = blockIdx.x * 256 + threadIdx.x;
    if (idx < NPPAD * NF) {
        int jp = idx / NF, f = idx - jp * NF;
        t[idx] = transform_padded(p + f * NP, jp);
    } else if (idx < NPPAD * NF + TBL_N) {
        int bin = idx - NPPAD * NF;
        float s, c;
        tbl_entry(bin, &s, &c);
        t[NPPAD * NF + 2 * bin]     = s;
        t[NPPAD * NF + 2 * bin + 1] = c;
    }
}

// Main kernel: lane = feature-pair (f, f+1) x ROWS rows; params in LDS (16KB only),
// tanh table gathered from global (L1-resident).
template <bool FUSE_XFORM>
__global__ __launch_bounds__(256)
void cdf_kernel(const float* __restrict__ x, const float* __restrict__ prm,
                float* __restrict__ out) {
    __shared__ __attribute__((aligned(16))) float ldsp[NPPAD * FT];  // [jp][FT]
    const int tid = threadIdx.x;
    const int pf  = tid & (NPF - 1);     // feature-pair index 0..15
    const int rg  = tid >> 4;            // 16 rowgroups
    const int f0  = blockIdx.x * FT;
    const int b0  = blockIdx.y * BLOCK_ROWS + rg * ROWS;
    const int fe  = f0 + 2 * pf;         // even feature of this lane's pair

    if constexpr (FUSE_XFORM) {
        for (int idx = tid; idx < NPPAD * FT; idx += 256) {
            int jp = idx >> 5, fl = idx & (FT - 1);
            ldsp[idx] = transform_padded(prm + (f0 + fl) * NP, jp);
        }
    } else {
        for (int idx = tid; idx < NPPAD * FT; idx += 256) {
            int jp = idx >> 5, fl = idx & (FT - 1);
            ldsp[idx] = prm[jp * NF + f0 + fl];
        }
    }

    v2f xin[ROWS];
#pragma unroll
    for (int r = 0; r < ROWS; ++r)
        xin[r] = *reinterpret_cast<const v2f*>(&x[(b0 + r) * NF + fe]);

    __syncthreads();

    const v2f K128 = {128.0f, 128.0f};
    const v2f KIdx = {1024.5f, 1024.5f};
    const v2f* __restrict__ tw = reinterpret_cast<const v2f*>(prm + NPPAD * NF);

    const float* Pp = ldsp + 2 * pf;
#define PRMV(JP) (*reinterpret_cast<const v2f*>(Pp + (JP) * FT))

    // tanh dispatch: non-FUSE -> hybrid (2 LUT via global + 1 exp); FUSE -> all exp
#define TANH_A(a) (FUSE_XFORM ? tanh_exp_pair(a) : tanh_lut_pair((a), tw, K128, KIdx))
#define TANH_B(a) tanh_exp_pair(a)

    v2f h0[ROWS], h1[ROWS], h2[ROWS];
    // ---- layer 0: w0..2 (jp 0..2), b0..2 (3..5), s0..2 (6..8) ----
    {
        v2f W0 = PRMV(0), W1 = PRMV(1), W2 = PRMV(2);
        v2f C0 = PRMV(3), C1 = PRMV(4), C2 = PRMV(5);
        v2f S0 = PRMV(6), S1 = PRMV(7), S2 = PRMV(8);
#pragma unroll
        for (int r = 0; r < ROWS; ++r) {
            v2f a0 = f_PP(xin[r], W0, C0);
            v2f a1 = f_PP(xin[r], W1, C1);
            v2f a2 = f_PP(xin[r], W2, C2);
            v2f T0 = TANH_A(a0);
            v2f T1 = TANH_A(a1);
            v2f T2 = TANH_B(a2);
            h0[r] = f_PP(S0, T0, a0);
            h1[r] = f_PP(S1, T1, a1);
            h2[r] = f_PP(S2, T2, a2);
        }
    }
    // ---- middle layers 1..7: base bp = 10+16*(li-1) ----
#pragma unroll
    for (int li = 1; li < 8; ++li) {
        const int bp = 10 + 16 * (li - 1);
        v2f W00 = PRMV(bp + 0), W01 = PRMV(bp + 1), W02 = PRMV(bp + 2);
        v2f W10 = PRMV(bp + 3), W11 = PRMV(bp + 4), W12 = PRMV(bp + 5);
        v2f W20 = PRMV(bp + 6), W21 = PRMV(bp + 7), W22 = PRMV(bp + 8);
        v2f C0  = PRMV(bp + 9), C1  = PRMV(bp + 10), C2 = PRMV(bp + 11);
        v2f S0  = PRMV(bp + 12), S1 = PRMV(bp + 13), S2 = PRMV(bp + 14);
#pragma unroll
        for (int r = 0; r < ROWS; ++r) {
            v2f a0 = f_PP(h0[r], W00, f_PP(h1[r], W01, f_PP(h2[r], W02, C0)));
            v2f a1 = f_PP(h0[r], W10, f_PP(h1[r], W11, f_PP(h2[r], W12, C1)));
            v2f a2 = f_PP(h0[r], W20, f_PP(h1[r], W21, f_PP(h2[r], W22, C2)));
            v2f T0 = TANH_A(a0);
            v2f T1 = TANH_A(a1);
            v2f T2 = TANH_B(a2);
            h0[r] = f_PP(S0, T0, a0);
            h1[r] = f_PP(S1, T1, a1);
            h2[r] = f_PP(S2, T2, a2);
        }
    }
    // ---- final layer: w (122..124), b (125); sigmoid on trans pipe ----
    {
        v2f W0 = PRMV(122), W1 = PRMV(123), W2 = PRMV(124), CB = PRMV(125);
#pragma unroll
        for (int r = 0; r < ROWS; ++r) {
            v2f a = f_PP(h0[r], W0, f_PP(h1[r], W1, f_PP(h2[r], W2, CB)));
            v2f o;
            o.x = sigmoid1(a.x);
            o.y = sigmoid1(a.y);
            *reinterpret_cast<v2f*>(&out[(b0 + r) * NF + fe]) = o;
        }
    }
#undef PRMV
#undef TANH_A
#undef TANH_B
}

extern "C" void kernel_launch(void* const* d_in, const int* in_sizes, int n_in,
                              void* d_out, int out_size, void* d_ws, size_t ws_size,
                              hipStream_t stream) {
    const float* x = (const float*)d_in[0];       // (B, 512) f32
    const float* p = (const float*)d_in[1];       // (512, 118) f32
    float* out = (float*)d_out;                   // (B, 512) f32

    const int B = in_sizes[0] / NF;               // 32768
    dim3 grid(NF / FT, B / BLOCK_ROWS);           // (16, 512)
    dim3 block(256);

    if (ws_size >= WS_NEED) {
        float* t = (float*)d_ws;
        int total = NPPAD * NF + TBL_N;
        xform_kernel<<<(total + 255) / 256, 256, 0, stream>>>(p, t);
        cdf_kernel<false><<<grid, block, 0, stream>>>(x, t, out);
    } else {
        cdf_kernel<true><<<grid, block, 0, stream>>>(x, p, out);
    }
}

// Round 11
// 103.498 us; speedup vs baseline: 2.5430x; 2.5430x over previous
//
#include <hip/hip_runtime.h>
#include <math.h>

#define NF 512         // feature count
#define NP 118         // raw params per feature
#define NPPAD 126      // padded: L0 at 0 (+1 pad), middle li at 10+16*(li-1), final at 122
#define FT 16          // features per block tile (8 feature-PAIRS per lane-group)
#define NPF 8          // feature-pairs per tile
#define ROWS 4         // rows per thread
#define BLOCK_ROWS 128 // 32 rowgroups * 4 rows
#define TBL_N 2048     // tanh secant bins over ~[-8,8] (h=1/128, accuracy-proven)
#define WS_NEED ((size_t)(NPPAD * NF + 2 * TBL_N) * sizeof(float))

typedef float v2f __attribute__((ext_vector_type(2)));

// plain packed fp32 FMA (feature-pair packing: every operand is a true pair)
__device__ __forceinline__ v2f f_PP(v2f a, v2f b, v2f c) {
    v2f d; asm("v_pk_fma_f32 %0, %1, %2, %3" : "=v"(d) : "v"(a), "v"(b), "v"(c)); return d;
}

__device__ __forceinline__ float fast_rcp(float x) { return __builtin_amdgcn_rcpf(x); }
__device__ __forceinline__ float exp2_fast(float x) {
#if __has_builtin(__builtin_amdgcn_exp2f)
    return __builtin_amdgcn_exp2f(x);
#else
    return __expf(x * 0.6931471805599453f);
#endif
}

// exp-path tanh (trans pipe): 3 VALU + 2 trans per scalar
__device__ __forceinline__ float tanh_exp1(float x) {
    float e = exp2_fast(x * 2.8853900817779268f);
    return fmaf(-2.0f, fast_rcp(e + 1.0f), 1.0f);
}
__device__ __forceinline__ v2f tanh_exp_pair(v2f a) {
    v2f t; t.x = tanh_exp1(a.x); t.y = tanh_exp1(a.y); return t;
}
__device__ __forceinline__ float sigmoid1(float x) {
    return fast_rcp(1.0f + exp2_fast(x * -1.4426950408889634f));
}

// LUT-path tanh (VALU + LDS pipes): secant table gather
__device__ __forceinline__ v2f tanh_lut_pair(v2f a, const v2f* __restrict__ tbl,
                                             v2f K128, v2f KIdx) {
    v2f xi = f_PP(a, K128, KIdx);
    unsigned i0 = (unsigned)__builtin_amdgcn_fmed3f(xi.x, 0.0f, (float)(TBL_N - 1));
    unsigned i1 = (unsigned)__builtin_amdgcn_fmed3f(xi.y, 0.0f, (float)(TBL_N - 1));
    v2f g0 = tbl[i0];
    v2f g1 = tbl[i1];
    v2f t;
    t.x = fmaf(a.x, g0.x, g0.y);
    t.y = fmaf(a.y, g1.x, g1.y);
    return t;
}

// ---- parameter transform ----
__device__ __forceinline__ float transform_one(float v, int j) {
    int cls;
    if (j < 3) cls = 0;
    else if (j < 6) cls = 1;
    else if (j < 9) cls = 2;
    else if (j < 114) { int k = (j - 9) % 15; cls = (k < 9) ? 0 : ((k < 12) ? 1 : 2); }
    else if (j < 117) cls = 0;
    else cls = 1;
    if (cls == 0) return fmaxf(v, 0.0f) + log1pf(expf(-fabsf(v)));  // stable softplus
    if (cls == 2) return tanhf(v);
    return v;
}

__device__ __forceinline__ bool map_padded(int jp, int* j) {
    if (jp < 9) { *j = jp; return true; }
    if (jp == 9) return false;
    if (jp < 122) {
        int k = (jp - 10) & 15, li = (jp - 10) >> 4;
        if (k == 15) return false;
        *j = 9 + 15 * li + k;
        return true;
    }
    *j = 114 + (jp - 122);
    return true;
}

__device__ __forceinline__ float transform_padded(const float* __restrict__ prow, int jp) {
    int j;
    if (!map_padded(jp, &j)) return 0.0f;
    return transform_one(prow[j], j);
}

// secant over centered bin b: x in [(b-1024.5)/128, (b-1023.5)/128)
__device__ __forceinline__ void tbl_entry(int b, float* s, float* c) {
    float xl = (float)b * (1.0f / 128.0f) - (1024.5f / 128.0f);
    float xr = xl + (1.0f / 128.0f);
    float t0 = tanhf(xl), t1 = tanhf(xr);
    float sl = (t1 - t0) * 128.0f;
    *s = sl;
    *c = fmaf(-sl, xl, t0);
}

// Kernel 1: padded+transformed params transposed t[jp*NF+f], then (s,c) table.
__global__ void xform_kernel(const float* __restrict__ p, float* __restrict__ t) {
    int idx = blockIdx.x * 256 + threadIdx.x;
    if (idx < NPPAD * NF) {
        int jp = idx / NF, f = idx - jp * NF;
        t[idx] = transform_padded(p + f * NP, jp);
    } else if (idx < NPPAD * NF + TBL_N) {
        int bin = idx - NPPAD * NF;
        float s, c;
        tbl_entry(bin, &s, &c);
        t[NPPAD * NF + 2 * bin]     = s;
        t[NPPAD * NF + 2 * bin + 1] = c;
    }
}

// Main kernel: lane = feature-pair (f, f+1) x ROWS rows; all pk ops plain.
template <bool FUSE_XFORM>
__global__ __launch_bounds__(256)
void cdf_kernel(const float* __restrict__ x, const float* __restrict__ prm,
                float* __restrict__ out) {
    __shared__ __attribute__((aligned(16))) float ldsp[NPPAD * FT];  // [jp][FT]
    __shared__ v2f tblv[TBL_N];                                      // (slope, intercept)
    const int tid = threadIdx.x;
    const int pf  = tid & (NPF - 1);     // feature-pair index 0..7
    const int rg  = tid >> 3;            // 32 rowgroups
    const int f0  = blockIdx.x * FT;
    const int b0  = blockIdx.y * BLOCK_ROWS + rg * ROWS;
    const int fe  = f0 + 2 * pf;         // even feature of this lane's pair

    if constexpr (FUSE_XFORM) {
        for (int idx = tid; idx < NPPAD * FT; idx += 256) {
            int jp = idx >> 4, fl = idx & (FT - 1);
            ldsp[idx] = transform_padded(prm + (f0 + fl) * NP, jp);
        }
        float* tf = (float*)tblv;
        for (int bin = tid; bin < TBL_N; bin += 256) {
            float s, c; tbl_entry(bin, &s, &c);
            tf[2 * bin] = s; tf[2 * bin + 1] = c;
        }
    } else {
        for (int idx = tid; idx < NPPAD * FT; idx += 256) {
            int jp = idx >> 4, fl = idx & (FT - 1);
            ldsp[idx] = prm[jp * NF + f0 + fl];
        }
        float* tf = (float*)tblv;
        const float* tw = prm + NPPAD * NF;
        for (int idx = tid; idx < 2 * TBL_N; idx += 256)
            tf[idx] = tw[idx];
    }

    v2f xin[ROWS];
#pragma unroll
    for (int r = 0; r < ROWS; ++r)
        xin[r] = *reinterpret_cast<const v2f*>(&x[(b0 + r) * NF + fe]);

    __syncthreads();

    const v2f K128 = {128.0f, 128.0f};
    const v2f KIdx = {1024.5f, 1024.5f};

    const float* Pp = ldsp + 2 * pf;
#define PRMV(JP) (*reinterpret_cast<const v2f*>(Pp + (JP) * FT))

    v2f h0[ROWS], h1[ROWS], h2[ROWS];
    // ---- layer 0: w0..2 (jp 0..2), b0..2 (3..5), s0..2 (6..8) ----
    {
        v2f W0 = PRMV(0), W1 = PRMV(1), W2 = PRMV(2);
        v2f C0 = PRMV(3), C1 = PRMV(4), C2 = PRMV(5);
        v2f S0 = PRMV(6), S1 = PRMV(7), S2 = PRMV(8);
#pragma unroll
        for (int r = 0; r < ROWS; ++r) {
            v2f a0 = f_PP(xin[r], W0, C0);
            v2f a1 = f_PP(xin[r], W1, C1);
            v2f a2 = f_PP(xin[r], W2, C2);
            v2f T0 = tanh_lut_pair(a0, tblv, K128, KIdx);
            v2f T1 = tanh_lut_pair(a1, tblv, K128, KIdx);
            v2f T2 = tanh_exp_pair(a2);
            h0[r] = f_PP(S0, T0, a0);
            h1[r] = f_PP(S1, T1, a1);
            h2[r] = f_PP(S2, T2, a2);
        }
    }
    // ---- middle layers 1..7: base bp = 10+16*(li-1): w row-major 0..8, b 9..11, s 12..14 ----
#pragma unroll
    for (int li = 1; li < 8; ++li) {
        const int bp = 10 + 16 * (li - 1);
        v2f W00 = PRMV(bp + 0), W01 = PRMV(bp + 1), W02 = PRMV(bp + 2);
        v2f W10 = PRMV(bp + 3), W11 = PRMV(bp + 4), W12 = PRMV(bp + 5);
        v2f W20 = PRMV(bp + 6), W21 = PRMV(bp + 7), W22 = PRMV(bp + 8);
        v2f C0  = PRMV(bp + 9), C1  = PRMV(bp + 10), C2 = PRMV(bp + 11);
        v2f S0  = PRMV(bp + 12), S1 = PRMV(bp + 13), S2 = PRMV(bp + 14);
#pragma unroll
        for (int r = 0; r < ROWS; ++r) {
            v2f a0 = f_PP(h0[r], W00, f_PP(h1[r], W01, f_PP(h2[r], W02, C0)));
            v2f a1 = f_PP(h0[r], W10, f_PP(h1[r], W11, f_PP(h2[r], W12, C1)));
            v2f a2 = f_PP(h0[r], W20, f_PP(h1[r], W21, f_PP(h2[r], W22, C2)));
            v2f T0 = tanh_lut_pair(a0, tblv, K128, KIdx);
            v2f T1 = tanh_lut_pair(a1, tblv, K128, KIdx);
            v2f T2 = tanh_exp_pair(a2);
            h0[r] = f_PP(S0, T0, a0);
            h1[r] = f_PP(S1, T1, a1);
            h2[r] = f_PP(S2, T2, a2);
        }
    }
    // ---- final layer: w (122..124), b (125); sigmoid on trans pipe ----
    {
        v2f W0 = PRMV(122), W1 = PRMV(123), W2 = PRMV(124), CB = PRMV(125);
#pragma unroll
        for (int r = 0; r < ROWS; ++r) {
            v2f a = f_PP(h0[r], W0, f_PP(h1[r], W1, f_PP(h2[r], W2, CB)));
            v2f o;
            o.x = sigmoid1(a.x);
            o.y = sigmoid1(a.y);
            *reinterpret_cast<v2f*>(&out[(b0 + r) * NF + fe]) = o;
        }
    }
#undef PRMV
}

extern "C" void kernel_launch(void* const* d_in, const int* in_sizes, int n_in,
                              void* d_out, int out_size, void* d_ws, size_t ws_size,
                              hipStream_t stream) {
    const float* x = (const float*)d_in[0];       // (B, 512) f32
    const float* p = (const float*)d_in[1];       // (512, 118) f32
    float* out = (float*)d_out;                   // (B, 512) f32

    const int B = in_sizes[0] / NF;               // 32768
    dim3 grid(NF / FT, B / BLOCK_ROWS);           // (32, 256)
    dim3 block(256);

    if (ws_size >= WS_NEED) {
        float* t = (float*)d_ws;
        int total = NPPAD * NF + TBL_N;
        xform_kernel<<<(total + 255) / 256, 256, 0, stream>>>(p, t);
        cdf_kernel<false><<<grid, block, 0, stream>>>(x, t, out);
    } else {
        cdf_kernel<true><<<grid, block, 0, stream>>>(x, p, out);
    }
}